// Round 5
// baseline (824.022 us; speedup 1.0000x reference)
//
#include <hip/hip_runtime.h>
#include <float.h>

// RankLoss round 5: LDS-transpose + lane-owns-row serial scan.
// R2-R4 post-mortems: kernel is latency/issue-bound (L3-warm replays run at the
// same ~130us as cold); compiler refuses register prefetch (VGPR stuck at 32);
// cross-lane butterfly chains (~400cy/unit of ds_bpermute round-trips) are
// unhideable. Fix: transpose 64-row tiles through per-wave LDS so each lane
// reduces its OWN row serially -> zero shuffles/ballots, exact tie handling.
// Double-buffered (2 reg chunks + 2 LDS bufs) inside a REAL runtime loop so
// the scheduler cannot sink the global loads across the back-edge.

constexpr int B     = 32768;
constexpr int C_ENT = 1000;
constexpr int C_REL = 500;
constexpr float LOG2E = 1.4426950408889634f;

__device__ inline float fexp2(float x) { return exp2f(x); }

// ---------------- stats kernel ----------------
// grid 2560 x 64 threads (1 wave/block). unit u: seg=u>>9 (0:s[0,500) 1:s[500,1000)
// 2:o[0,500) 3:o[500,1000) 4:r), rb=u&511 -> rows rb*64..rb*64+63.
// Chunk = 5 float4-cols x 64 rows (4KB). 25 chunks/unit exactly.
// LDS tile stride 21 floats (odd -> 2-way bank aliasing on b32 = free).

__global__ __launch_bounds__(64, 4) void stats_kernel(
    const float* __restrict__ s, const float* __restrict__ r, const float* __restrict__ o,
    const int* __restrict__ st, const int* __restrict__ rt, const int* __restrict__ ot,
    float4* __restrict__ stat4, float* __restrict__ xtg) {
  __shared__ float lds0[64 * 21];
  __shared__ float lds1[64 * 21];
  const int l = threadIdx.x;
  const int u = blockIdx.x;
  const int seg = u >> 9, rb = u & 511;

  const float* mat; const int* tgt; int stride_f, coff_f;
  if (seg < 2)      { mat = s; tgt = st; stride_f = C_ENT; coff_f = (seg & 1) * 500; }
  else if (seg < 4) { mat = o; tgt = ot; stride_f = C_ENT; coff_f = (seg & 1) * 500; }
  else              { mat = r; tgt = rt; stride_f = C_REL; coff_f = 0; }

  const int row0 = rb * 64;
  const float* segbase = mat + (size_t)row0 * stride_f + coff_f;

  // 5 load slots per lane: flat = j*64+l over (64 rows x 5 f4-cols); rl=flat/5, c=flat%5.
  // Global: 16B-aligned everywhere (row strides 4000/2000B, coff 2000B, chunk step 80B).
  const float4* bp[5];
  int wa[5];
#pragma unroll
  for (int j = 0; j < 5; ++j) {
    const int f = j * 64 + l;
    const int rl = f / 5, c = f - 5 * rl;
    bp[j] = (const float4*)(segbase + (size_t)rl * stride_f) + c;
    wa[j] = rl * 21 + c * 4;
  }
  const float* rp0 = &lds0[l * 21];
  const float* rp1 = &lds1[l * 21];

  const int t = tgt[row0 + l];
  int d = t - coff_f;              // countdown to target col; wrong half -> never hits
  float xt = 0.f;
  float m1 = -FLT_MAX, m2 = -FLT_MAX, Z = 0.f;
  int idx = 0, kb = 0;

  // per-chunk compute: lane-serial over its own row's 20 floats
  auto compute = [&](const float* __restrict__ rowp) {
    float a[20];
#pragma unroll
    for (int c = 0; c < 20; ++c) a[c] = rowp[c];
    {  // target capture (branchless, 1 clamped LDS read)
      const unsigned du = (unsigned)d;
      const float cand = rowp[du < 20u ? du : 19u];
      if (du < 20u) xt = cand;
      d -= 20;
    }
    // chunk max (tree, depth ~5) -> exp base available early
    const float b0 = fmaxf(fmaxf(a[0],  a[1]),  fmaxf(a[2],  a[3]));
    const float b1 = fmaxf(fmaxf(a[4],  a[5]),  fmaxf(a[6],  a[7]));
    const float b2 = fmaxf(fmaxf(a[8],  a[9]),  fmaxf(a[10], a[11]));
    const float b3 = fmaxf(fmaxf(a[12], a[13]), fmaxf(a[14], a[15]));
    const float b4 = fmaxf(fmaxf(a[16], a[17]), fmaxf(a[18], a[19]));
    const float mc  = fmaxf(fmaxf(b0, b1), fmaxf(fmaxf(b2, b3), b4));
    const float m1n = fmaxf(m1, mc);
    const float nb  = -m1n * LOG2E;
    float z0 = 0.f, z1 = 0.f, z2 = 0.f, z3 = 0.f;
#pragma unroll
    for (int c = 0; c < 20; c += 4) {
      z0 += fexp2(fmaf(a[c],     LOG2E, nb));
      z1 += fexp2(fmaf(a[c + 1], LOG2E, nb));
      z2 += fexp2(fmaf(a[c + 2], LOG2E, nb));
      z3 += fexp2(fmaf(a[c + 3], LOG2E, nb));
    }
    const float zc = (z0 + z1) + (z2 + z3);
    // online rescale; first chunk: m1=-FLT_MAX -> scale 0, Z=0 -> Z=zc (exact)
    Z = fmaf(Z, fexp2((m1 - m1n) * LOG2E), zc);
    // serial top2/argmax scan: dup -> m2=m1 naturally; strict > keeps 1st argmax
    int lpos = 0;
    const float m1b = m1;
#pragma unroll
    for (int c = 0; c < 20; ++c) {
      const float av = a[c];
      m2 = fmaxf(m2, fminf(m1, av));
      const bool g = av > m1;
      m1 = fmaxf(m1, av);
      lpos = g ? c : lpos;        // c is inline-const
    }
    idx = (m1 > m1b) ? kb + lpos : idx;
    kb += 20;
  };
  auto stage = [&](float* __restrict__ wb, const float4 v0, const float4 v1,
                   const float4 v2, const float4 v3, const float4 v4) {
    wb[wa[0]] = v0.x; wb[wa[0]+1] = v0.y; wb[wa[0]+2] = v0.z; wb[wa[0]+3] = v0.w;
    wb[wa[1]] = v1.x; wb[wa[1]+1] = v1.y; wb[wa[1]+2] = v1.z; wb[wa[1]+3] = v1.w;
    wb[wa[2]] = v2.x; wb[wa[2]+1] = v2.y; wb[wa[2]+2] = v2.z; wb[wa[2]+3] = v2.w;
    wb[wa[3]] = v3.x; wb[wa[3]+1] = v3.y; wb[wa[3]+2] = v3.z; wb[wa[3]+3] = v3.w;
    wb[wa[4]] = v4.x; wb[wa[4]+1] = v4.y; wb[wa[4]+2] = v4.z; wb[wa[4]+3] = v4.w;
  };

  float4 P0,P1,P2,P3,P4, Q0,Q1,Q2,Q3,Q4;
  // prologue: chunks 0..3 (bp[j][5k] = chunk k slot j; offsets are immediates)
  P0 = bp[0][0];  P1 = bp[1][0];  P2 = bp[2][0];  P3 = bp[3][0];  P4 = bp[4][0];
  Q0 = bp[0][5];  Q1 = bp[1][5];  Q2 = bp[2][5];  Q3 = bp[3][5];  Q4 = bp[4][5];
  stage(lds0, P0, P1, P2, P3, P4);                                  // chunk 0
  P0 = bp[0][10]; P1 = bp[1][10]; P2 = bp[2][10]; P3 = bp[3][10]; P4 = bp[4][10]; // 2
  stage(lds1, Q0, Q1, Q2, Q3, Q4);                                  // chunk 1
  Q0 = bp[0][15]; Q1 = bp[1][15]; Q2 = bp[2][15]; Q3 = bp[3][15]; Q4 = bp[4][15]; // 3

  // steady state: pair p handles chunks 2p,2p+1; loads run 4 chunks ahead.
  for (int p = 0; p < 10; ++p) {
    compute(rp0);                                                   // chunk 2p
    stage(lds0, P0, P1, P2, P3, P4);                                // chunk 2p+2
    P0 = bp[0][20]; P1 = bp[1][20]; P2 = bp[2][20]; P3 = bp[3][20]; P4 = bp[4][20]; // 2p+4
    compute(rp1);                                                   // chunk 2p+1
    stage(lds1, Q0, Q1, Q2, Q3, Q4);                                // chunk 2p+3
    Q0 = bp[0][25]; Q1 = bp[1][25]; Q2 = bp[2][25]; Q3 = bp[3][25]; Q4 = bp[4][25]; // 2p+5
    bp[0] += 10; bp[1] += 10; bp[2] += 10; bp[3] += 10; bp[4] += 10;
  }
  // peeled pair (chunks 20,21) + epilogue (22,23,24)
  compute(rp0);                                                     // 20
  stage(lds0, P0, P1, P2, P3, P4);                                  // 22
  P0 = bp[0][20]; P1 = bp[1][20]; P2 = bp[2][20]; P3 = bp[3][20]; P4 = bp[4][20]; // 24
  compute(rp1);                                                     // 21
  stage(lds1, Q0, Q1, Q2, Q3, Q4);                                  // 23
  compute(rp0);                                                     // 22
  stage(lds0, P0, P1, P2, P3, P4);                                  // 24
  compute(rp1);                                                     // 23
  compute(rp0);                                                     // 24

  const int gr = seg * B + row0 + l;
  stat4[gr] = make_float4(m1, m2, Z, __int_as_float(coff_f + idx));
  xtg[gr] = xt;
}

// ---------------- combine ----------------

__device__ inline void merge_halves(float4 a, float4 b,
                                    float& m1, float& m2, float& Z, int& idx) {
  m1 = fmaxf(a.x, b.x);
  Z  = a.z * fexp2((a.x - m1) * LOG2E) + b.z * fexp2((b.x - m1) * LOG2E);
  m2 = fmaxf(fminf(a.x, b.x), (a.x >= b.x) ? a.y : b.y);   // ==-case -> m2 = m1 (dup)
  idx = (b.x > a.x) ? __float_as_int(b.w) : __float_as_int(a.w);  // tie -> half0 (lower)
}

__global__ __launch_bounds__(256) void combine_kernel(
    const float4* __restrict__ st4, const float* __restrict__ xtg,
    const int* __restrict__ st, const int* __restrict__ rt, const int* __restrict__ ot,
    float* __restrict__ out) {
  const int row = blockIdx.x * 256 + threadIdx.x;   // grid = B/256
  const float4 sa = st4[row],         sb = st4[B + row];
  const float4 oa = st4[2 * B + row], ob = st4[3 * B + row];
  const float4 rr = st4[4 * B + row];
  const int ts = st[row], tr = rt[row], to = ot[row];
  const float xs = (ts < 500) ? xtg[row]           : xtg[B + row];
  const float xo = (to < 500) ? xtg[2 * B + row]   : xtg[3 * B + row];
  const float xr = xtg[4 * B + row];

  float sm1, sm2, sZ; int si;
  float om1, om2, oZ; int oi;
  merge_halves(sa, sb, sm1, sm2, sZ, si);
  merge_halves(oa, ob, om1, om2, oZ, oi);
  const float rm1 = rr.x, rm2 = rr.y, rZ = rr.z;
  const int ri = __float_as_int(rr.w);

  const float sI = 1.0f / sZ, rI = 1.0f / rZ, oI = 1.0f / oZ;
  const float sp1 = fexp2((sm2 - sm1) * LOG2E) * sI;
  const float rp1 = fexp2((rm2 - rm1) * LOG2E) * rI;
  const float op1 = fexp2((om2 - om1) * LOG2E) * oI;
  const float spt = fexp2((xs - sm1) * LOG2E) * sI;
  const float rpt = fexp2((xr - rm1) * LOG2E) * rI;
  const float opt = fexp2((xo - om1) * LOG2E) * oI;

  const float gt   = spt * rpt * opt;
  const float top1 = sI * rI * oI;
  // second-smallest of 8 top2-products = min of the three one-swap products
  const float c1 = sI  * rp1 * op1;
  const float c2 = sp1 * rI  * op1;
  const float c3 = sp1 * rp1 * oI;
  const float second = fminf(c1, fminf(c2, c3));
  const bool cond = (si == ts) && (ri == tr) && (oi == to);
  const float pre = cond ? second : top1;
  float val = fmaxf(1.0f - gt + pre, 0.0f) * (1.0f / (float)B);

#pragma unroll
  for (int off = 32; off; off >>= 1) val += __shfl_xor(val, off);
  __shared__ float red[4];
  if ((threadIdx.x & 63) == 0) red[threadIdx.x >> 6] = val;
  __syncthreads();
  if (threadIdx.x == 0)
    atomicAdd(out, (red[0] + red[1]) + (red[2] + red[3]));
}

// ---------------- fallback (ws too small) ----------------

__device__ inline void combine_stats(float& m1, int& i1, float& m2, float& Z,
                                     float bm1, int bi1, float bm2, float bZ) {
  bool bwin = (bm1 > m1) || (bm1 == m1 && bi1 < i1);
  float wm1 = bwin ? bm1 : m1;
  int   wi1 = bwin ? bi1 : i1;
  float wm2 = bwin ? bm2 : m2;
  float lm1 = bwin ? m1  : bm1;
  float wZ  = bwin ? bZ  : Z;
  float lZ  = bwin ? Z   : bZ;
  m1 = wm1; i1 = wi1;
  m2 = fmaxf(wm2, lm1);
  Z  = wZ + lZ * __expf(lm1 - wm1);
}

template<int NK, int C4>
__device__ inline void row_stats(const float* __restrict__ row, int lane, int target,
                                 float& p_top1, float& p_top2, int& amax, float& p_tgt) {
  const float4* row4 = (const float4*)row;
  float4 v[NK];
#pragma unroll
  for (int k = 0; k < NK; ++k) {
    int i2 = lane + 64 * k;
    v[k] = (i2 < C4) ? row4[i2] : make_float4(-FLT_MAX, -FLT_MAX, -FLT_MAX, -FLT_MAX);
  }
  float m1 = -FLT_MAX, m2 = -FLT_MAX;
  int   i1 = 0x7fffffff;
#pragma unroll
  for (int k = 0; k < NK; ++k) {
    int base = 4 * (lane + 64 * k);
    float a0 = v[k].x, a1 = v[k].y, a2 = v[k].z, a3 = v[k].w;
    if (a0 > m1) { m2 = m1; m1 = a0; i1 = base;     } else if (a0 > m2) m2 = a0;
    if (a1 > m1) { m2 = m1; m1 = a1; i1 = base + 1; } else if (a1 > m2) m2 = a1;
    if (a2 > m1) { m2 = m1; m1 = a2; i1 = base + 2; } else if (a2 > m2) m2 = a2;
    if (a3 > m1) { m2 = m1; m1 = a3; i1 = base + 3; } else if (a3 > m2) m2 = a3;
  }
  float Z = 0.f;
#pragma unroll
  for (int k = 0; k < NK; ++k) {
    Z += __expf(v[k].x - m1); Z += __expf(v[k].y - m1);
    Z += __expf(v[k].z - m1); Z += __expf(v[k].w - m1);
  }
#pragma unroll
  for (int off = 32; off > 0; off >>= 1) {
    float bm1 = __shfl_xor(m1, off);
    int   bi1 = __shfl_xor(i1, off);
    float bm2 = __shfl_xor(m2, off);
    float bZ  = __shfl_xor(Z,  off);
    combine_stats(m1, i1, m2, Z, bm1, bi1, bm2, bZ);
  }
  float invZ = 1.0f / Z;
  float xv   = row[target];
  p_top1 = invZ;
  p_top2 = __expf(m2 - m1) * invZ;
  p_tgt  = __expf(xv - m1) * invZ;
  amax   = i1;
}

__global__ __launch_bounds__(256) void rank_loss_atomic_kernel(
    const float* __restrict__ s, const float* __restrict__ r, const float* __restrict__ o,
    const int* __restrict__ st, const int* __restrict__ rt, const int* __restrict__ ot,
    float* __restrict__ out) {
  const int wid  = threadIdx.x >> 6;
  const int lane = threadIdx.x & 63;
  const int row  = blockIdx.x * 4 + wid;

  const int tS = st[row], tR = rt[row], tO = ot[row];
  float sp0, sp1, spt; int sa;
  float rp0, rp1, rpt; int ra;
  float op0, op1, opt; int oa;
  row_stats<4, C_ENT / 4>(s + (size_t)row * C_ENT, lane, tS, sp0, sp1, sa, spt);
  row_stats<2, C_REL / 4>(r + (size_t)row * C_REL, lane, tR, rp0, rp1, ra, rpt);
  row_stats<4, C_ENT / 4>(o + (size_t)row * C_ENT, lane, tO, op0, op1, oa, opt);

  if (lane == 0) {
    float gt   = spt * rpt * opt;
    float top1 = sp0 * rp0 * op0;
    float c1 = sp0 * rp1 * op1;
    float c2 = sp1 * rp0 * op1;
    float c3 = sp1 * rp1 * op0;
    float second = fminf(c1, fminf(c2, c3));
    bool cond = (sa == tS) && (ra == tR) && (oa == tO);
    float pre = cond ? second : top1;
    atomicAdd(out, fmaxf(1.0f - gt + pre, 0.0f) * (1.0f / (float)B));
  }
}

extern "C" void kernel_launch(void* const* d_in, const int* in_sizes, int n_in,
                              void* d_out, int out_size, void* d_ws, size_t ws_size,
                              hipStream_t stream) {
  const float* s  = (const float*)d_in[0];
  const float* r  = (const float*)d_in[1];
  const float* o  = (const float*)d_in[2];
  const int*   st = (const int*)d_in[3];
  const int*   rt = (const int*)d_in[4];
  const int*   ot = (const int*)d_in[5];
  float* out = (float*)d_out;

  hipMemsetAsync(d_out, 0, sizeof(float), stream);
  const size_t statBytes = (size_t)5 * B * sizeof(float4);   // 2.62 MB
  const size_t xtBytes   = (size_t)5 * B * sizeof(float);    // 0.66 MB
  if (ws_size >= statBytes + xtBytes) {
    float4* stat4 = (float4*)d_ws;
    float*  xtg   = (float*)((char*)d_ws + statBytes);
    stats_kernel<<<2560, 64, 0, stream>>>(s, r, o, st, rt, ot, stat4, xtg);
    combine_kernel<<<B / 256, 256, 0, stream>>>(stat4, xtg, st, rt, ot, out);
  } else {
    rank_loss_atomic_kernel<<<B / 4, 256, 0, stream>>>(s, r, o, st, rt, ot, out);
  }
}